// Round 10
// baseline (137.164 us; speedup 1.0000x reference)
//
#include <hip/hip_runtime.h>

#define S_LEN 256
#define H_DIM 768
#define T_HEADS 13
#define WN 1664
#define NEGV 1.0e12f

typedef __bf16 bf16x8 __attribute__((ext_vector_type(8)));
typedef float f32x4 __attribute__((ext_vector_type(4)));
typedef float f32x16 __attribute__((ext_vector_type(16)));
typedef unsigned int u32x4 __attribute__((ext_vector_type(4)));

static __device__ __forceinline__ ushort f2bf(float x) {
  unsigned u = __float_as_uint(x);
  return (ushort)((u + 0x7FFFu + ((u >> 16) & 1u)) >> 16);
}

// async global->LDS, 16B per lane; LDS dest = wave-uniform base + lane*16
#define GLOAD16(gp, lp)                                                        \
  __builtin_amdgcn_global_load_lds(                                            \
      (const __attribute__((address_space(1))) unsigned int*)(gp),             \
      (__attribute__((address_space(3))) unsigned int*)(lp), 16, 0, 0)

#define PREP_LHS_BLOCKS 6144  // (64*256*768)/8/256

// ---- prep (fused): lhs f32->bf16 copy  +  W transpose f32->bf16 ----
__global__ __launch_bounds__(256) void prep_all(const float* __restrict__ lhs,
                                                const float* __restrict__ W,
                                                ushort* __restrict__ lhsb,
                                                ushort* __restrict__ Wt) {
  const int tid = threadIdx.x;
  if (blockIdx.x < PREP_LHS_BLOCKS) {
    size_t base = ((size_t)blockIdx.x * 256 + tid) * 8;
    float4 v0 = *reinterpret_cast<const float4*>(lhs + base);
    float4 v1 = *reinterpret_cast<const float4*>(lhs + base + 4);
    uint4 u;
    u.x = f2bf(v0.x) | ((unsigned)f2bf(v0.y) << 16);
    u.y = f2bf(v0.z) | ((unsigned)f2bf(v0.w) << 16);
    u.z = f2bf(v1.x) | ((unsigned)f2bf(v1.y) << 16);
    u.w = f2bf(v1.z) | ((unsigned)f2bf(v1.w) << 16);
    *reinterpret_cast<uint4*>(lhsb + base) = u;
    return;
  }
  __shared__ ushort T[64][68];
  const int blk = blockIdx.x - PREP_LHS_BLOCKS;
  const int k0 = (blk % 12) * 64, c0 = (blk / 12) * 64;
#pragma unroll
  for (int p = 0; p < 4; ++p) {
    int f = p * 256 + tid;
    int r = f >> 4, cg = f & 15;
    float4 v = *reinterpret_cast<const float4*>(W + (size_t)(k0 + r) * WN + c0 + cg * 4);
    T[r][cg * 4 + 0] = f2bf(v.x); T[r][cg * 4 + 1] = f2bf(v.y);
    T[r][cg * 4 + 2] = f2bf(v.z); T[r][cg * 4 + 3] = f2bf(v.w);
  }
  __syncthreads();
  const int orow = tid >> 2, kq = tid & 3;
  ushort tmp[16];
#pragma unroll
  for (int j = 0; j < 16; ++j) tmp[j] = T[kq * 16 + j][orow];
  uint4 u0, u1;
  u0.x = tmp[0] | ((unsigned)tmp[1] << 16);  u0.y = tmp[2] | ((unsigned)tmp[3] << 16);
  u0.z = tmp[4] | ((unsigned)tmp[5] << 16);  u0.w = tmp[6] | ((unsigned)tmp[7] << 16);
  u1.x = tmp[8] | ((unsigned)tmp[9] << 16);  u1.y = tmp[10] | ((unsigned)tmp[11] << 16);
  u1.z = tmp[12] | ((unsigned)tmp[13] << 16); u1.w = tmp[14] | ((unsigned)tmp[15] << 16);
  ushort* dst = Wt + (size_t)(c0 + orow) * H_DIM + k0 + kq * 16;
  *reinterpret_cast<uint4*>(dst) = u0;
  *reinterpret_cast<uint4*>(dst + 8) = u1;
}

// ---- K1: GEMM via global_load_lds, 32x32x16 MFMA + bias + RoPE -> Qb, Kb ----
// LDS swizzle (both-sides involution): staged unit at LDS pos p holds global
// unit p^(row&7); read global unit g at pos g^(row&7).
__global__ __launch_bounds__(256, 4) void gemm_rope(
    const ushort* __restrict__ lhsb, const ushort* __restrict__ Wt,
    const float* __restrict__ bias, ushort* __restrict__ Qb,
    ushort* __restrict__ Kb) {
  const int x = blockIdx.x;        // 0..1663
  const int xcd = x & 7;
  const int seq = x >> 3;          // 0..207
  const int grp = seq / 104;
  const int loc = seq % 104;       // 4 batches * 2 halves * 13 heads
  const int b = (xcd + 8 * grp) * 4 + (loc / 26);
  const int rem = loc % 26;
  const int mrow0 = (rem / 13) * 128;
  const int th = rem % 13;
  const int tid = threadIdx.x;
  const int w = tid >> 6;
  const int lane = tid & 63;
  const int l31 = lane & 31;
  const int hi2 = lane >> 5;
  const int lrow8 = lane >> 3;                 // 0..7 (row within 8-row stripe)
  const int lc16 = (lane & 7) ^ lrow8;         // pre-swizzled source unit

  __shared__ union {
    struct { ushort A[128 * 64]; ushort W[128 * 64]; } p1;  // 16K + 16K (linear)
    struct { ushort Q[128][72]; ushort K[128][72]; } p2;    // 36K bounce
  } sm;

  const ushort* Ag = lhsb + ((size_t)b * S_LEN + mrow0) * H_DIM;
  const ushort* Wg = Wt + (size_t)th * 128 * H_DIM;

  f32x16 c2[4];
#pragma unroll
  for (int ni = 0; ni < 4; ++ni) c2[ni] = (f32x16){};

  for (int k0 = 0; k0 < H_DIM; k0 += 64) {
#pragma unroll
    for (int j = 0; j < 4; ++j) {
      const int r0 = w * 32 + j * 8;  // wave-uniform
      GLOAD16(Ag + (size_t)(r0 + lrow8) * H_DIM + k0 + lc16 * 8, &sm.p1.A[r0 * 64]);
      GLOAD16(Wg + (size_t)(r0 + lrow8) * H_DIM + k0 + lc16 * 8, &sm.p1.W[r0 * 64]);
    }
    __syncthreads();  // drains vmcnt -> tile ready
#pragma unroll
    for (int ks = 0; ks < 4; ++ks) {
      const int arow = w * 32 + l31;
      bf16x8 af = *reinterpret_cast<const bf16x8*>(
          &sm.p1.A[arow * 64 + (((ks * 2 + hi2) ^ (l31 & 7)) * 8)]);
#pragma unroll
      for (int ni = 0; ni < 4; ++ni) {
        const int brow = ni * 32 + l31;
        bf16x8 bfr = *reinterpret_cast<const bf16x8*>(
            &sm.p1.W[brow * 64 + (((ks * 2 + hi2) ^ (l31 & 7)) * 8)]);
        c2[ni] = __builtin_amdgcn_mfma_f32_32x32x16_bf16(af, bfr, c2[ni], 0, 0, 0);
      }
    }
    __syncthreads();  // protect LDS overwrite next iter
  }

  // ---- bias + RoPE into LDS bounce (32x32 C/D: col=l31+32*ni, row map below) ----
  float bj2[4];
#pragma unroll
  for (int ni = 0; ni < 4; ++ni) bj2[ni] = bias[th * 128 + ni * 32 + l31];

  float inv2[2];
#pragma unroll
  for (int ni = 0; ni < 2; ++ni)
    inv2[ni] = exp2f(-(float)(ni * 16 + (l31 >> 1)) * 0.4152410118609203f);  // log2(1e4)/32
  const float sgn = (l31 & 1) ? 1.0f : -1.0f;

#pragma unroll
  for (int reg = 0; reg < 16; ++reg) {
    int ml = w * 32 + (reg & 3) + 8 * (reg >> 2) + 4 * hi2;  // verified 32x32 row map
    int m_seq = mrow0 + ml;
#pragma unroll
    for (int ni = 0; ni < 2; ++ni) {
      float sv, cv;
      __sincosf((float)m_seq * inv2[ni], &sv, &cv);
      {  // q half: cols 0..63 (ni 0,1)
        float v = c2[ni][reg] + bj2[ni];
        float o = __shfl_xor(v, 1);
        sm.p2.Q[ml][ni * 32 + l31] = f2bf(v * cv + sgn * o * sv);
      }
      {  // k half: cols 64..127 (ni 2,3)
        float v = c2[ni + 2][reg] + bj2[ni + 2];
        float o = __shfl_xor(v, 1);
        sm.p2.K[ml][ni * 32 + l31] = f2bf(v * cv + sgn * o * sv);
      }
    }
  }
  __syncthreads();

  // ---- NT full-line flush: bypass L2 so A/Wt stay resident ----
  ushort* qbase = Qb + ((size_t)(b * T_HEADS + th) * S_LEN + mrow0) * 64;
  ushort* kbase = Kb + ((size_t)(b * T_HEADS + th) * S_LEN + mrow0) * 64;
#pragma unroll
  for (int p = 0; p < 4; ++p) {
    int f = p * 256 + tid;
    int row = f >> 3, c8 = f & 7;
    __builtin_nontemporal_store(
        *reinterpret_cast<const u32x4*>(&sm.p2.Q[row][c8 * 8]),
        reinterpret_cast<u32x4*>(qbase + (size_t)row * 64 + c8 * 8));
    __builtin_nontemporal_store(
        *reinterpret_cast<const u32x4*>(&sm.p2.K[row][c8 * 8]),
        reinterpret_cast<u32x4*>(kbase + (size_t)row * 64 + c8 * 8));
  }
}

// ---- K2: logits = Q @ K^T per (b,head); no LDS, no barriers; full-line NT stores ----
__global__ __launch_bounds__(256, 2) void qk_logits(
    const ushort* __restrict__ Qb, const ushort* __restrict__ Kb,
    const float* __restrict__ amask, float* __restrict__ out) {
  const int x = blockIdx.x;        // 0..831
  const int xcd = x & 7;
  const int seq = x >> 3;          // 0..103
  const int grp = seq / 52;
  const int loc = seq % 52;        // 4 batches * 13 heads
  const int b = (xcd + 8 * grp) * 4 + loc / 13;
  const int th = loc % 13;
  const int bid = b * T_HEADS + th;
  const int tid = threadIdx.x;
  const int w = tid >> 6;
  const int lane = tid & 63;
  const int l31 = lane & 31;
  const int hi2 = lane >> 5;

  const ushort* qbase = Qb + ((size_t)bid * S_LEN) * 64;
  const ushort* kbase = Kb + ((size_t)bid * S_LEN) * 64;

  bf16x8 qf2[2][4];
#pragma unroll
  for (int mtile = 0; mtile < 2; ++mtile)
#pragma unroll
    for (int ks = 0; ks < 4; ++ks)
      qf2[mtile][ks] = *reinterpret_cast<const bf16x8*>(
          qbase + (size_t)(w * 64 + mtile * 32 + l31) * 64 + ks * 16 + hi2 * 8);

  const size_t outbase = (size_t)bid * (S_LEN * (size_t)S_LEN);
#pragma unroll 1
  for (int nt = 0; nt < 8; ++nt) {
    bf16x8 kf2[4];
#pragma unroll
    for (int ks = 0; ks < 4; ++ks)
      kf2[ks] = *reinterpret_cast<const bf16x8*>(
          kbase + (size_t)(nt * 32 + l31) * 64 + ks * 16 + hi2 * 8);

    const int ncol = nt * 32 + l31;
    const float pad = amask[b * S_LEN + ncol];
    const float sub = (1.0f - pad) * NEGV;

#pragma unroll
    for (int mtile = 0; mtile < 2; ++mtile) {
      f32x16 c2 = {};
#pragma unroll
      for (int ks = 0; ks < 4; ++ks)
        c2 = __builtin_amdgcn_mfma_f32_32x32x16_bf16(qf2[mtile][ks], kf2[ks], c2, 0, 0, 0);

#pragma unroll
      for (int reg = 0; reg < 16; ++reg) {
        int m = w * 64 + mtile * 32 + (reg & 3) + 8 * (reg >> 2) + 4 * hi2;
        float v = c2[reg] * pad - sub;
        if (m > ncol) v -= NEGV;  // tril(.., -1)
        __builtin_nontemporal_store(v * 0.125f, &out[outbase + (size_t)m * S_LEN + ncol]);
      }
    }
  }
}

// ---- fallback fused kernel (R4-class, known-correct) ----
__global__ __launch_bounds__(256, 1) void gp_fallback(
    const float* __restrict__ lhs, const float* __restrict__ Wd,
    const float* __restrict__ bias, const float* __restrict__ amask,
    float* __restrict__ out) {
  const int bid0 = blockIdx.x;
  const int bid = (bid0 & 7) * 104 + (bid0 >> 3);
  const int b = bid / T_HEADS;
  const int th = bid % T_HEADS;
  const int wcol0 = th * 128;
  const int tid = threadIdx.x;
  const int w = tid >> 6;
  const int lane = tid & 63;
  const int lo = lane & 15;
  const int hi = lane >> 4;
  const int l31 = lane & 31;
  const int hi2 = lane >> 5;

  __shared__ union {
    struct { ushort A[256][72]; ushort W[128][72]; } p1;
    struct { ushort Q[256][72]; ushort K[256][72]; } p2;
  } sm;
  __shared__ float mask_s[256];

  mask_s[tid] = amask[b * S_LEN + tid];

  f32x4 acc[4][8];
#pragma unroll
  for (int mi = 0; mi < 4; ++mi)
#pragma unroll
    for (int ni = 0; ni < 8; ++ni) acc[mi][ni] = (f32x4){0.f, 0.f, 0.f, 0.f};

  const float* Ab = lhs + (size_t)b * (S_LEN * H_DIM);
  const int wc4 = tid & 31, wrg = tid >> 5;
  for (int k0 = 0; k0 < H_DIM; k0 += 64) {
#pragma unroll
    for (int p = 0; p < 16; ++p) {
      int f = p * 256 + tid;
      int m = f >> 4, c4 = f & 15;
      float4 v = *reinterpret_cast<const float4*>(Ab + (size_t)m * H_DIM + k0 + c4 * 4);
      *reinterpret_cast<ushort4*>(&sm.p1.A[m][c4 * 4]) =
          make_ushort4(f2bf(v.x), f2bf(v.y), f2bf(v.z), f2bf(v.w));
    }
    {
      ushort wt[8][4];
#pragma unroll
      for (int r8 = 0; r8 < 8; ++r8) {
        float4 v = *reinterpret_cast<const float4*>(
            Wd + (size_t)(k0 + wrg * 8 + r8) * WN + wcol0 + wc4 * 4);
        wt[r8][0] = f2bf(v.x); wt[r8][1] = f2bf(v.y);
        wt[r8][2] = f2bf(v.z); wt[r8][3] = f2bf(v.w);
      }
#pragma unroll
      for (int cc = 0; cc < 4; ++cc) {
        *reinterpret_cast<ushort4*>(&sm.p1.W[wc4 * 4 + cc][wrg * 8]) =
            make_ushort4(wt[0][cc], wt[1][cc], wt[2][cc], wt[3][cc]);
        *reinterpret_cast<ushort4*>(&sm.p1.W[wc4 * 4 + cc][wrg * 8 + 4]) =
            make_ushort4(wt[4][cc], wt[5][cc], wt[6][cc], wt[7][cc]);
      }
    }
    __syncthreads();
#pragma unroll
    for (int kk = 0; kk < 2; ++kk) {
      bf16x8 af[4];
#pragma unroll
      for (int mi = 0; mi < 4; ++mi)
        af[mi] = *reinterpret_cast<const bf16x8*>(&sm.p1.A[w * 64 + mi * 16 + lo][kk * 32 + hi * 8]);
#pragma unroll
      for (int ni = 0; ni < 8; ++ni) {
        bf16x8 bfr = *reinterpret_cast<const bf16x8*>(&sm.p1.W[ni * 16 + lo][kk * 32 + hi * 8]);
#pragma unroll
        for (int mi = 0; mi < 4; ++mi)
          acc[mi][ni] = __builtin_amdgcn_mfma_f32_16x16x32_bf16(af[mi], bfr, acc[mi][ni], 0, 0, 0);
      }
    }
    __syncthreads();
  }

  float bj[8];
#pragma unroll
  for (int ni = 0; ni < 8; ++ni) bj[ni] = bias[wcol0 + ni * 16 + lo];

  float inv_[4];
#pragma unroll
  for (int ii = 0; ii < 4; ++ii)
    inv_[ii] = exp2f(-(float)(ii * 8 + (lo >> 1)) * 0.4152410118609203f);
  const float sgn = (lo & 1) ? 1.0f : -1.0f;

#pragma unroll
  for (int mi = 0; mi < 4; ++mi) {
#pragma unroll
    for (int r = 0; r < 4; ++r) {
      int m = w * 64 + mi * 16 + hi * 4 + r;
#pragma unroll
      for (int ii = 0; ii < 4; ++ii) {
        float sv, cv;
        __sincosf((float)m * inv_[ii], &sv, &cv);
        {
          float v = acc[mi][ii][r] + bj[ii];
          float o = __shfl_xor(v, 1);
          sm.p2.Q[m][ii * 16 + lo] = f2bf(v * cv + sgn * o * sv);
        }
        {
          float v = acc[mi][ii + 4][r] + bj[ii + 4];
          float o = __shfl_xor(v, 1);
          sm.p2.K[m][ii * 16 + lo] = f2bf(v * cv + sgn * o * sv);
        }
      }
    }
  }
  __syncthreads();

  bf16x8 qf2[2][4];
#pragma unroll
  for (int mtile = 0; mtile < 2; ++mtile)
#pragma unroll
    for (int ks = 0; ks < 4; ++ks)
      qf2[mtile][ks] = *reinterpret_cast<const bf16x8*>(
          &sm.p2.Q[w * 64 + mtile * 32 + l31][ks * 16 + hi2 * 8]);

  const size_t outbase = (size_t)bid * (S_LEN * (size_t)S_LEN);
#pragma unroll 1
  for (int nt = 0; nt < 8; ++nt) {
    bf16x8 kf2[4];
#pragma unroll
    for (int ks = 0; ks < 4; ++ks)
      kf2[ks] = *reinterpret_cast<const bf16x8*>(
          &sm.p2.K[nt * 32 + l31][ks * 16 + hi2 * 8]);

    const int ncol = nt * 32 + l31;
    const float pad = mask_s[ncol];
    const float sub = (1.0f - pad) * NEGV;

#pragma unroll
    for (int mtile = 0; mtile < 2; ++mtile) {
      f32x16 c2 = {};
#pragma unroll
      for (int ks = 0; ks < 4; ++ks)
        c2 = __builtin_amdgcn_mfma_f32_32x32x16_bf16(qf2[mtile][ks], kf2[ks], c2, 0, 0, 0);

#pragma unroll
      for (int reg = 0; reg < 16; ++reg) {
        int m = w * 64 + mtile * 32 + (reg & 3) + 8 * (reg >> 2) + 4 * hi2;
        float v = c2[reg] * pad - sub;
        if (m > ncol) v -= NEGV;
        __builtin_nontemporal_store(v * 0.125f, &out[outbase + (size_t)m * S_LEN + ncol]);
      }
    }
  }
}

extern "C" void kernel_launch(void* const* d_in, const int* in_sizes, int n_in,
                              void* d_out, int out_size, void* d_ws, size_t ws_size,
                              hipStream_t stream) {
  const float* lhs = (const float*)d_in[0];    // (64,256,768) f32
  const float* Wd = (const float*)d_in[1];     // (768,1664) f32
  const float* bias = (const float*)d_in[2];   // (1664,) f32
  const float* amask = (const float*)d_in[3];  // (64,256) f32
  float* out = (float*)d_out;                  // (64,13,256,256) f32

  const size_t lhsb_elems = (size_t)64 * S_LEN * H_DIM;
  const size_t wt_elems = (size_t)WN * H_DIM;
  const size_t qk_elems = (size_t)64 * T_HEADS * S_LEN * 64;
  const size_t need_split = (lhsb_elems + wt_elems + 2 * qk_elems) * sizeof(ushort);

  if (ws_size >= need_split) {
    ushort* lhsb = (ushort*)d_ws;
    ushort* wt = lhsb + lhsb_elems;
    ushort* qb = wt + wt_elems;
    ushort* kb = qb + qk_elems;
    prep_all<<<dim3(PREP_LHS_BLOCKS + 12 * 26), 256, 0, stream>>>(lhs, Wd, lhsb, wt);
    gemm_rope<<<dim3(128 * T_HEADS), 256, 0, stream>>>(lhsb, wt, bias, qb, kb);
    qk_logits<<<dim3(64 * T_HEADS), 256, 0, stream>>>(qb, kb, amask, out);
  } else {
    gp_fallback<<<dim3(64 * T_HEADS), 256, 0, stream>>>(lhs, Wd, bias, amask, out);
  }
}

// Round 11
// 117.008 us; speedup vs baseline: 1.1723x; 1.1723x over previous
//
#include <hip/hip_runtime.h>

#define S_LEN 256
#define H_DIM 768
#define T_HEADS 13
#define WN 1664
#define NEGV 1.0e12f

typedef __bf16 bf16x8 __attribute__((ext_vector_type(8)));
typedef float f32x4 __attribute__((ext_vector_type(4)));
typedef float f32x16 __attribute__((ext_vector_type(16)));
typedef unsigned int u32x4 __attribute__((ext_vector_type(4)));
typedef int i32x8 __attribute__((ext_vector_type(8)));

static __device__ __forceinline__ ushort f2bf(float x) {
  unsigned u = __float_as_uint(x);
  return (ushort)((u + 0x7FFFu + ((u >> 16) & 1u)) >> 16);
}

// async global->LDS, 16B per lane; LDS dest = wave-uniform base + lane*16
#define GLOAD16(gp, lp)                                                        \
  __builtin_amdgcn_global_load_lds(                                            \
      (const __attribute__((address_space(1))) unsigned int*)(gp),             \
      (__attribute__((address_space(3))) unsigned int*)(lp), 16, 0, 0)

#define PREP_LHS_BLOCKS 6144   // (64*256*768)/8/256
#define PREP_WT_BLOCKS 312     // 12 * 26
#define PREP_ROPE_BLOCKS 16

// ---- prep (fused): lhs f32->fp8 copy + W transpose f32->fp8 + RoPE table ----
__global__ __launch_bounds__(256) void prep_all(const float* __restrict__ lhs,
                                                const float* __restrict__ W,
                                                unsigned char* __restrict__ lhs8,
                                                unsigned char* __restrict__ wt8,
                                                float2* __restrict__ rope) {
  const int tid = threadIdx.x;
  const unsigned bx = blockIdx.x;
  if (bx < PREP_LHS_BLOCKS) {
    size_t base = ((size_t)bx * 256 + tid) * 8;
    float4 v0 = *reinterpret_cast<const float4*>(lhs + base);
    float4 v1 = *reinterpret_cast<const float4*>(lhs + base + 4);
    int d0 = __builtin_amdgcn_cvt_pk_fp8_f32(v0.x, v0.y, 0, false);
    d0 = __builtin_amdgcn_cvt_pk_fp8_f32(v0.z, v0.w, d0, true);
    int d1 = __builtin_amdgcn_cvt_pk_fp8_f32(v1.x, v1.y, 0, false);
    d1 = __builtin_amdgcn_cvt_pk_fp8_f32(v1.z, v1.w, d1, true);
    uint2 u = make_uint2((unsigned)d0, (unsigned)d1);
    *reinterpret_cast<uint2*>(lhs8 + base) = u;
    return;
  }
  if (bx < PREP_LHS_BLOCKS + PREP_WT_BLOCKS) {
    __shared__ float T[64][68];
    const int blk = bx - PREP_LHS_BLOCKS;
    const int k0 = (blk % 12) * 64, c0 = (blk / 12) * 64;
#pragma unroll
    for (int p = 0; p < 4; ++p) {
      int f = p * 256 + tid;
      int r = f >> 4, cg = f & 15;
      float4 v = *reinterpret_cast<const float4*>(W + (size_t)(k0 + r) * WN + c0 + cg * 4);
      T[r][cg * 4 + 0] = v.x; T[r][cg * 4 + 1] = v.y;
      T[r][cg * 4 + 2] = v.z; T[r][cg * 4 + 3] = v.w;
    }
    __syncthreads();
    const int orow = tid >> 2, kq = tid & 3;
    float tf[16];
#pragma unroll
    for (int j = 0; j < 16; ++j) tf[j] = T[kq * 16 + j][orow];
    int d[4];
#pragma unroll
    for (int q = 0; q < 4; ++q) {
      d[q] = __builtin_amdgcn_cvt_pk_fp8_f32(tf[q * 4], tf[q * 4 + 1], 0, false);
      d[q] = __builtin_amdgcn_cvt_pk_fp8_f32(tf[q * 4 + 2], tf[q * 4 + 3], d[q], true);
    }
    uint4 u = make_uint4((unsigned)d[0], (unsigned)d[1], (unsigned)d[2], (unsigned)d[3]);
    *reinterpret_cast<uint4*>(wt8 + (size_t)(c0 + orow) * H_DIM + k0 + kq * 16) = u;
    return;
  }
  // RoPE table: rope[m][c] = (cos(m*inv[c>>1]), sin(m*inv[c>>1])), m<256, c<64
  const int blk = bx - (PREP_LHS_BLOCKS + PREP_WT_BLOCKS);
  const int row = blk * 16 + (tid >> 4);
  const int cq = (tid & 15) * 4;
#pragma unroll
  for (int q = 0; q < 4; ++q) {
    int c = cq + q;
    float inv = exp2f(-(float)(c >> 1) * 0.4152410118609203f);  // log2(1e4)/32
    float sv, cv;
    __sincosf((float)row * inv, &sv, &cv);
    rope[(size_t)row * 64 + c] = make_float2(cv, sv);
  }
}

// fp8 MFMA operand: row-slice read with unit-XOR swizzle (both-sides involution)
static __device__ __forceinline__ i32x8 frag8(const unsigned char* base, int row,
                                              int ks, int hi2, int l31) {
  union { u32x4 h[2]; i32x8 v; } u;
  const int u0 = (ks * 4 + hi2 * 2 + 0) ^ (l31 & 7);
  const int u1 = (ks * 4 + hi2 * 2 + 1) ^ (l31 & 7);
  u.h[0] = *reinterpret_cast<const u32x4*>(base + row * 128 + u0 * 16);
  u.h[1] = *reinterpret_cast<const u32x4*>(base + row * 128 + u1 * 16);
  return u.v;
}

// ---- K1: fp8 MX GEMM (BM=128, BN=128=one head, BK=128) + bias + RoPE(table) ----
__global__ __launch_bounds__(256, 4) void gemm_rope(
    const unsigned char* __restrict__ lhs8, const unsigned char* __restrict__ wt8,
    const float* __restrict__ bias, const float2* __restrict__ rope,
    ushort* __restrict__ Qb, ushort* __restrict__ Kb) {
  const int x = blockIdx.x;        // 0..1663
  const int xcd = x & 7;
  const int seq = x >> 3;          // 0..207
  const int grp = seq / 104;
  const int loc = seq % 104;       // 4 batches * 2 halves * 13 heads
  const int b = (xcd + 8 * grp) * 4 + (loc / 26);
  const int rem = loc % 26;
  const int mrow0 = (rem / 13) * 128;
  const int th = rem % 13;
  const int tid = threadIdx.x;
  const int w = tid >> 6;
  const int lane = tid & 63;
  const int l31 = lane & 31;
  const int hi2 = lane >> 5;
  const int lr8 = lane >> 3;              // 0..7 (row within 8-row stripe)
  const int lsu = (lane & 7) ^ lr8;       // pre-swizzled source unit (16B units)

  __shared__ union {
    struct { unsigned char A[128 * 128]; unsigned char W[128 * 128]; } p1;  // 16K+16K
    struct { ushort Q[128][72]; ushort K[128][72]; } p2;                     // 36K
  } sm;

  const unsigned char* Ag = lhs8 + ((size_t)b * S_LEN + mrow0) * H_DIM;
  const unsigned char* Wg = wt8 + (size_t)th * 128 * H_DIM;

  f32x16 c2[4];
#pragma unroll
  for (int ni = 0; ni < 4; ++ni) c2[ni] = (f32x16){};

  for (int k0 = 0; k0 < H_DIM; k0 += 128) {
#pragma unroll
    for (int j = 0; j < 4; ++j) {
      const int r0 = w * 32 + j * 8;  // wave-uniform; 8 rows x 128B = 1KB per gload
      GLOAD16(Ag + (size_t)(r0 + lr8) * H_DIM + k0 + lsu * 16, &sm.p1.A[r0 * 128]);
      GLOAD16(Wg + (size_t)(r0 + lr8) * H_DIM + k0 + lsu * 16, &sm.p1.W[r0 * 128]);
    }
    __syncthreads();  // drains vmcnt -> tile ready
#pragma unroll
    for (int ks = 0; ks < 2; ++ks) {
      i32x8 a = frag8(sm.p1.A, w * 32 + l31, ks, hi2, l31);
#pragma unroll
      for (int ni = 0; ni < 4; ++ni) {
        i32x8 bb = frag8(sm.p1.W, ni * 32 + l31, ks, hi2, l31);
        // fmtA=0 (fp8 e4m3), fmtB=0, unit E8M0 scales (0x7F = 2^0)
        c2[ni] = __builtin_amdgcn_mfma_scale_f32_32x32x64_f8f6f4(
            a, bb, c2[ni], 0, 0, 0, 0x7F, 0, 0x7F);
      }
    }
    __syncthreads();  // protect LDS overwrite next iter
  }

  // ---- bias + RoPE (table) into LDS bounce ----
  float bj2[4];
#pragma unroll
  for (int ni = 0; ni < 4; ++ni) bj2[ni] = bias[th * 128 + ni * 32 + l31];
  const float sgn = (l31 & 1) ? 1.0f : -1.0f;

#pragma unroll
  for (int reg = 0; reg < 16; ++reg) {
    int ml = w * 32 + (reg & 3) + 8 * (reg >> 2) + 4 * hi2;  // verified 32x32 row map
    int m_seq = mrow0 + ml;
#pragma unroll
    for (int ni = 0; ni < 2; ++ni) {
      float2 cs = rope[(size_t)m_seq * 64 + ni * 32 + l31];
      {  // q half: cols 0..63 (ni 0,1)
        float v = c2[ni][reg] + bj2[ni];
        float o = __shfl_xor(v, 1);
        sm.p2.Q[ml][ni * 32 + l31] = f2bf(v * cs.x + sgn * o * cs.y);
      }
      {  // k half: cols 64..127 (ni 2,3)
        float v = c2[ni + 2][reg] + bj2[ni + 2];
        float o = __shfl_xor(v, 1);
        sm.p2.K[ml][ni * 32 + l31] = f2bf(v * cs.x + sgn * o * cs.y);
      }
    }
  }
  __syncthreads();

  // ---- NT full-line flush: bypass L2 so A/W stay resident ----
  ushort* qbase = Qb + ((size_t)(b * T_HEADS + th) * S_LEN + mrow0) * 64;
  ushort* kbase = Kb + ((size_t)(b * T_HEADS + th) * S_LEN + mrow0) * 64;
#pragma unroll
  for (int p = 0; p < 4; ++p) {
    int f = p * 256 + tid;
    int row = f >> 3, c8 = f & 7;
    __builtin_nontemporal_store(
        *reinterpret_cast<const u32x4*>(&sm.p2.Q[row][c8 * 8]),
        reinterpret_cast<u32x4*>(qbase + (size_t)row * 64 + c8 * 8));
    __builtin_nontemporal_store(
        *reinterpret_cast<const u32x4*>(&sm.p2.K[row][c8 * 8]),
        reinterpret_cast<u32x4*>(kbase + (size_t)row * 64 + c8 * 8));
  }
}

// ---- K2: logits = Q @ K^T per (b,head); no LDS, no barriers; full-line NT stores ----
__global__ __launch_bounds__(256, 2) void qk_logits(
    const ushort* __restrict__ Qb, const ushort* __restrict__ Kb,
    const float* __restrict__ amask, float* __restrict__ out) {
  const int x = blockIdx.x;        // 0..831
  const int xcd = x & 7;
  const int seq = x >> 3;          // 0..103
  const int grp = seq / 52;
  const int loc = seq % 52;        // 4 batches * 13 heads
  const int b = (xcd + 8 * grp) * 4 + loc / 13;
  const int th = loc % 13;
  const int bid = b * T_HEADS + th;
  const int tid = threadIdx.x;
  const int w = tid >> 6;
  const int lane = tid & 63;
  const int l31 = lane & 31;
  const int hi2 = lane >> 5;

  const ushort* qbase = Qb + ((size_t)bid * S_LEN) * 64;
  const ushort* kbase = Kb + ((size_t)bid * S_LEN) * 64;

  bf16x8 qf2[2][4];
#pragma unroll
  for (int mtile = 0; mtile < 2; ++mtile)
#pragma unroll
    for (int ks = 0; ks < 4; ++ks)
      qf2[mtile][ks] = *reinterpret_cast<const bf16x8*>(
          qbase + (size_t)(w * 64 + mtile * 32 + l31) * 64 + ks * 16 + hi2 * 8);

  const size_t outbase = (size_t)bid * (S_LEN * (size_t)S_LEN);
#pragma unroll 1
  for (int nt = 0; nt < 8; ++nt) {
    bf16x8 kf2[4];
#pragma unroll
    for (int ks = 0; ks < 4; ++ks)
      kf2[ks] = *reinterpret_cast<const bf16x8*>(
          kbase + (size_t)(nt * 32 + l31) * 64 + ks * 16 + hi2 * 8);

    const int ncol = nt * 32 + l31;
    const float pad = amask[b * S_LEN + ncol];
    const float sub = (1.0f - pad) * NEGV;

#pragma unroll
    for (int mtile = 0; mtile < 2; ++mtile) {
      f32x16 c2 = {};
#pragma unroll
      for (int ks = 0; ks < 4; ++ks)
        c2 = __builtin_amdgcn_mfma_f32_32x32x16_bf16(qf2[mtile][ks], kf2[ks], c2, 0, 0, 0);

#pragma unroll
      for (int reg = 0; reg < 16; ++reg) {
        int m = w * 64 + mtile * 32 + (reg & 3) + 8 * (reg >> 2) + 4 * hi2;
        float v = c2[reg] * pad - sub;
        if (m > ncol) v -= NEGV;  // tril(.., -1)
        __builtin_nontemporal_store(v * 0.125f, &out[outbase + (size_t)m * S_LEN + ncol]);
      }
    }
  }
}

// ---- fallback fused kernel (known-correct, no workspace) ----
__global__ __launch_bounds__(256, 1) void gp_fallback(
    const float* __restrict__ lhs, const float* __restrict__ Wd,
    const float* __restrict__ bias, const float* __restrict__ amask,
    float* __restrict__ out) {
  const int bid0 = blockIdx.x;
  const int bid = (bid0 & 7) * 104 + (bid0 >> 3);
  const int b = bid / T_HEADS;
  const int th = bid % T_HEADS;
  const int wcol0 = th * 128;
  const int tid = threadIdx.x;
  const int w = tid >> 6;
  const int lane = tid & 63;
  const int lo = lane & 15;
  const int hi = lane >> 4;
  const int l31 = lane & 31;
  const int hi2 = lane >> 5;

  __shared__ union {
    struct { ushort A[256][72]; ushort W[128][72]; } p1;
    struct { ushort Q[256][72]; ushort K[256][72]; } p2;
  } sm;
  __shared__ float mask_s[256];

  mask_s[tid] = amask[b * S_LEN + tid];

  f32x4 acc[4][8];
#pragma unroll
  for (int mi = 0; mi < 4; ++mi)
#pragma unroll
    for (int ni = 0; ni < 8; ++ni) acc[mi][ni] = (f32x4){0.f, 0.f, 0.f, 0.f};

  const float* Ab = lhs + (size_t)b * (S_LEN * H_DIM);
  const int wc4 = tid & 31, wrg = tid >> 5;
  for (int k0 = 0; k0 < H_DIM; k0 += 64) {
#pragma unroll
    for (int p = 0; p < 16; ++p) {
      int f = p * 256 + tid;
      int m = f >> 4, c4 = f & 15;
      float4 v = *reinterpret_cast<const float4*>(Ab + (size_t)m * H_DIM + k0 + c4 * 4);
      *reinterpret_cast<ushort4*>(&sm.p1.A[m][c4 * 4]) =
          make_ushort4(f2bf(v.x), f2bf(v.y), f2bf(v.z), f2bf(v.w));
    }
    {
      ushort wt[8][4];
#pragma unroll
      for (int r8 = 0; r8 < 8; ++r8) {
        float4 v = *reinterpret_cast<const float4*>(
            Wd + (size_t)(k0 + wrg * 8 + r8) * WN + wcol0 + wc4 * 4);
        wt[r8][0] = f2bf(v.x); wt[r8][1] = f2bf(v.y);
        wt[r8][2] = f2bf(v.z); wt[r8][3] = f2bf(v.w);
      }
#pragma unroll
      for (int cc = 0; cc < 4; ++cc) {
        *reinterpret_cast<ushort4*>(&sm.p1.W[wc4 * 4 + cc][wrg * 8]) =
            make_ushort4(wt[0][cc], wt[1][cc], wt[2][cc], wt[3][cc]);
        *reinterpret_cast<ushort4*>(&sm.p1.W[wc4 * 4 + cc][wrg * 8 + 4]) =
            make_ushort4(wt[4][cc], wt[5][cc], wt[6][cc], wt[7][cc]);
      }
    }
    __syncthreads();
#pragma unroll
    for (int kk = 0; kk < 2; ++kk) {
      bf16x8 af[4];
#pragma unroll
      for (int mi = 0; mi < 4; ++mi)
        af[mi] = *reinterpret_cast<const bf16x8*>(&sm.p1.A[w * 64 + mi * 16 + lo][kk * 32 + hi * 8]);
#pragma unroll
      for (int ni = 0; ni < 8; ++ni) {
        bf16x8 bfr = *reinterpret_cast<const bf16x8*>(&sm.p1.W[ni * 16 + lo][kk * 32 + hi * 8]);
#pragma unroll
        for (int mi = 0; mi < 4; ++mi)
          acc[mi][ni] = __builtin_amdgcn_mfma_f32_16x16x32_bf16(af[mi], bfr, acc[mi][ni], 0, 0, 0);
      }
    }
    __syncthreads();
  }

  float bj[8];
#pragma unroll
  for (int ni = 0; ni < 8; ++ni) bj[ni] = bias[wcol0 + ni * 16 + lo];

  float inv_[4];
#pragma unroll
  for (int ii = 0; ii < 4; ++ii)
    inv_[ii] = exp2f(-(float)(ii * 8 + (lo >> 1)) * 0.4152410118609203f);
  const float sgn = (lo & 1) ? 1.0f : -1.0f;

#pragma unroll
  for (int mi = 0; mi < 4; ++mi) {
#pragma unroll
    for (int r = 0; r < 4; ++r) {
      int m = w * 64 + mi * 16 + hi * 4 + r;
#pragma unroll
      for (int ii = 0; ii < 4; ++ii) {
        float sv, cv;
        __sincosf((float)m * inv_[ii], &sv, &cv);
        {
          float v = acc[mi][ii][r] + bj[ii];
          float o = __shfl_xor(v, 1);
          sm.p2.Q[m][ii * 16 + lo] = f2bf(v * cv + sgn * o * sv);
        }
        {
          float v = acc[mi][ii + 4][r] + bj[ii + 4];
          float o = __shfl_xor(v, 1);
          sm.p2.K[m][ii * 16 + lo] = f2bf(v * cv + sgn * o * sv);
        }
      }
    }
  }
  __syncthreads();

  bf16x8 qf2[2][4];
#pragma unroll
  for (int mtile = 0; mtile < 2; ++mtile)
#pragma unroll
    for (int ks = 0; ks < 4; ++ks)
      qf2[mtile][ks] = *reinterpret_cast<const bf16x8*>(
          &sm.p2.Q[w * 64 + mtile * 32 + l31][ks * 16 + hi2 * 8]);

  const size_t outbase = (size_t)bid * (S_LEN * (size_t)S_LEN);
#pragma unroll 1
  for (int nt = 0; nt < 8; ++nt) {
    bf16x8 kf2[4];
#pragma unroll
    for (int ks = 0; ks < 4; ++ks)
      kf2[ks] = *reinterpret_cast<const bf16x8*>(
          &sm.p2.K[nt * 32 + l31][ks * 16 + hi2 * 8]);

    const int ncol = nt * 32 + l31;
    const float pad = mask_s[ncol];
    const float sub = (1.0f - pad) * NEGV;

#pragma unroll
    for (int mtile = 0; mtile < 2; ++mtile) {
      f32x16 c2 = {};
#pragma unroll
      for (int ks = 0; ks < 4; ++ks)
        c2 = __builtin_amdgcn_mfma_f32_32x32x16_bf16(qf2[mtile][ks], kf2[ks], c2, 0, 0, 0);

#pragma unroll
      for (int reg = 0; reg < 16; ++reg) {
        int m = w * 64 + mtile * 32 + (reg & 3) + 8 * (reg >> 2) + 4 * hi2;
        float v = c2[reg] * pad - sub;
        if (m > ncol) v -= NEGV;
        __builtin_nontemporal_store(v * 0.125f, &out[outbase + (size_t)m * S_LEN + ncol]);
      }
    }
  }
}

extern "C" void kernel_launch(void* const* d_in, const int* in_sizes, int n_in,
                              void* d_out, int out_size, void* d_ws, size_t ws_size,
                              hipStream_t stream) {
  const float* lhs = (const float*)d_in[0];    // (64,256,768) f32
  const float* Wd = (const float*)d_in[1];     // (768,1664) f32
  const float* bias = (const float*)d_in[2];   // (1664,) f32
  const float* amask = (const float*)d_in[3];  // (64,256) f32
  float* out = (float*)d_out;                  // (64,13,256,256) f32

  const size_t rope_bytes = (size_t)256 * 64 * sizeof(float2);        // 128 KB
  const size_t qk_elems = (size_t)64 * T_HEADS * S_LEN * 64;          // 13.63M ushort
  const size_t lhs8_bytes = (size_t)64 * S_LEN * H_DIM;               // 12.58 MB
  const size_t wt8_bytes = (size_t)WN * H_DIM;                        // 1.28 MB
  const size_t need = rope_bytes + 2 * qk_elems * sizeof(ushort) + lhs8_bytes + wt8_bytes;

  if (ws_size >= need) {
    float2* rope = (float2*)d_ws;
    ushort* qb = (ushort*)((char*)d_ws + rope_bytes);
    ushort* kb = qb + qk_elems;
    unsigned char* lhs8 = (unsigned char*)(kb + qk_elems);
    unsigned char* wt8 = lhs8 + lhs8_bytes;
    prep_all<<<dim3(PREP_LHS_BLOCKS + PREP_WT_BLOCKS + PREP_ROPE_BLOCKS), 256, 0, stream>>>(
        lhs, Wd, lhs8, wt8, rope);
    gemm_rope<<<dim3(128 * T_HEADS), 256, 0, stream>>>(lhs8, wt8, bias, rope, qb, kb);
    qk_logits<<<dim3(64 * T_HEADS), 256, 0, stream>>>(qb, kb, amask, out);
  } else {
    gp_fallback<<<dim3(64 * T_HEADS), 256, 0, stream>>>(lhs, Wd, bias, amask, out);
  }
}

// Round 12
// 98.906 us; speedup vs baseline: 1.3868x; 1.1830x over previous
//
#include <hip/hip_runtime.h>

#define S_LEN 256
#define H_DIM 768
#define T_HEADS 13
#define WN 1664
#define NEGV 1.0e12f

typedef __bf16 bf16x8 __attribute__((ext_vector_type(8)));
typedef float f32x4 __attribute__((ext_vector_type(4)));
typedef float f32x16 __attribute__((ext_vector_type(16)));
typedef unsigned int u32x4 __attribute__((ext_vector_type(4)));
typedef int i32x8 __attribute__((ext_vector_type(8)));

static __device__ __forceinline__ ushort f2bf(float x) {
  unsigned u = __float_as_uint(x);
  return (ushort)((u + 0x7FFFu + ((u >> 16) & 1u)) >> 16);
}

// 8 bf16 (packed in 4 dwords) -> 8 fp8 e4m3 (2 dwords)
static __device__ __forceinline__ uint2 fp8x8_from_bf16x8(u32x4 v) {
  float f[8];
#pragma unroll
  for (int i = 0; i < 4; ++i) {
    f[2 * i] = __uint_as_float((v[i] & 0xFFFFu) << 16);
    f[2 * i + 1] = __uint_as_float(v[i] & 0xFFFF0000u);
  }
  int lo = __builtin_amdgcn_cvt_pk_fp8_f32(f[0], f[1], 0, false);
  lo = __builtin_amdgcn_cvt_pk_fp8_f32(f[2], f[3], lo, true);
  int hi = __builtin_amdgcn_cvt_pk_fp8_f32(f[4], f[5], 0, false);
  hi = __builtin_amdgcn_cvt_pk_fp8_f32(f[6], f[7], hi, true);
  return make_uint2((unsigned)lo, (unsigned)hi);
}

// async global->LDS, 16B per lane; LDS dest = wave-uniform base + lane*16
#define GLOAD16(gp, lp)                                                        \
  __builtin_amdgcn_global_load_lds(                                            \
      (const __attribute__((address_space(1))) unsigned int*)(gp),             \
      (__attribute__((address_space(3))) unsigned int*)(lp), 16, 0, 0)

#define PREP_LHS_BLOCKS 6144   // (64*256*768)/8/256
#define PREP_WT_BLOCKS 312     // 12 * 26
#define PREP_ROPE_BLOCKS 16

// ---- prep (fused): lhs f32->fp8 copy + W transpose f32->fp8 + RoPE table ----
__global__ __launch_bounds__(256) void prep_all(const float* __restrict__ lhs,
                                                const float* __restrict__ W,
                                                unsigned char* __restrict__ lhs8,
                                                unsigned char* __restrict__ wt8,
                                                float2* __restrict__ rope) {
  const int tid = threadIdx.x;
  const unsigned bx = blockIdx.x;
  if (bx < PREP_LHS_BLOCKS) {
    size_t base = ((size_t)bx * 256 + tid) * 8;
    float4 v0 = *reinterpret_cast<const float4*>(lhs + base);
    float4 v1 = *reinterpret_cast<const float4*>(lhs + base + 4);
    int d0 = __builtin_amdgcn_cvt_pk_fp8_f32(v0.x, v0.y, 0, false);
    d0 = __builtin_amdgcn_cvt_pk_fp8_f32(v0.z, v0.w, d0, true);
    int d1 = __builtin_amdgcn_cvt_pk_fp8_f32(v1.x, v1.y, 0, false);
    d1 = __builtin_amdgcn_cvt_pk_fp8_f32(v1.z, v1.w, d1, true);
    uint2 u = make_uint2((unsigned)d0, (unsigned)d1);
    *reinterpret_cast<uint2*>(lhs8 + base) = u;
    return;
  }
  if (bx < PREP_LHS_BLOCKS + PREP_WT_BLOCKS) {
    __shared__ float T[64][68];
    const int blk = bx - PREP_LHS_BLOCKS;
    const int k0 = (blk % 12) * 64, c0 = (blk / 12) * 64;
#pragma unroll
    for (int p = 0; p < 4; ++p) {
      int f = p * 256 + tid;
      int r = f >> 4, cg = f & 15;
      float4 v = *reinterpret_cast<const float4*>(W + (size_t)(k0 + r) * WN + c0 + cg * 4);
      T[r][cg * 4 + 0] = v.x; T[r][cg * 4 + 1] = v.y;
      T[r][cg * 4 + 2] = v.z; T[r][cg * 4 + 3] = v.w;
    }
    __syncthreads();
    const int orow = tid >> 2, kq = tid & 3;
    float tf[16];
#pragma unroll
    for (int j = 0; j < 16; ++j) tf[j] = T[kq * 16 + j][orow];
    int d[4];
#pragma unroll
    for (int q = 0; q < 4; ++q) {
      d[q] = __builtin_amdgcn_cvt_pk_fp8_f32(tf[q * 4], tf[q * 4 + 1], 0, false);
      d[q] = __builtin_amdgcn_cvt_pk_fp8_f32(tf[q * 4 + 2], tf[q * 4 + 3], d[q], true);
    }
    uint4 u = make_uint4((unsigned)d[0], (unsigned)d[1], (unsigned)d[2], (unsigned)d[3]);
    *reinterpret_cast<uint4*>(wt8 + (size_t)(c0 + orow) * H_DIM + k0 + kq * 16) = u;
    return;
  }
  // RoPE table: rope[m][c] = (cos(m*inv[c>>1]), sin(m*inv[c>>1])), m<256, c<64
  const int blk = bx - (PREP_LHS_BLOCKS + PREP_WT_BLOCKS);
  const int row = blk * 16 + (tid >> 4);
  const int cq = (tid & 15) * 4;
#pragma unroll
  for (int q = 0; q < 4; ++q) {
    int c = cq + q;
    float inv = exp2f(-(float)(c >> 1) * 0.4152410118609203f);  // log2(1e4)/32
    float sv, cv;
    __sincosf((float)row * inv, &sv, &cv);
    rope[(size_t)row * 64 + c] = make_float2(cv, sv);
  }
}

// fp8 MFMA operand: row-slice read with unit-XOR swizzle (both-sides involution)
static __device__ __forceinline__ i32x8 frag8(const unsigned char* base, int row,
                                              int ks, int hi2, int l31) {
  union { u32x4 h[2]; i32x8 v; } u;
  const int u0 = (ks * 4 + hi2 * 2 + 0) ^ (l31 & 7);
  const int u1 = (ks * 4 + hi2 * 2 + 1) ^ (l31 & 7);
  u.h[0] = *reinterpret_cast<const u32x4*>(base + row * 128 + u0 * 16);
  u.h[1] = *reinterpret_cast<const u32x4*>(base + row * 128 + u1 * 16);
  return u.v;
}

// ---- K1: fp8 MX GEMM (BM=128, BN=128=one head, BK=128) + bias + RoPE(table) ----
// Qb/Kb written as fp8 (cached stores; per-XCD 3.4MB fits L2 for K2's reads).
__global__ __launch_bounds__(256, 4) void gemm_rope(
    const unsigned char* __restrict__ lhs8, const unsigned char* __restrict__ wt8,
    const float* __restrict__ bias, const float2* __restrict__ rope,
    unsigned char* __restrict__ Qb, unsigned char* __restrict__ Kb) {
  const int x = blockIdx.x;        // 0..1663
  const int xcd = x & 7;
  const int seq = x >> 3;          // 0..207
  const int grp = seq / 104;
  const int loc = seq % 104;       // 4 batches * 2 halves * 13 heads
  const int b = (xcd + 8 * grp) * 4 + (loc / 26);
  const int rem = loc % 26;
  const int mrow0 = (rem / 13) * 128;
  const int th = rem % 13;
  const int tid = threadIdx.x;
  const int w = tid >> 6;
  const int lane = tid & 63;
  const int l31 = lane & 31;
  const int hi2 = lane >> 5;
  const int lr8 = lane >> 3;              // 0..7 (row within 8-row stripe)
  const int lsu = (lane & 7) ^ lr8;       // pre-swizzled source unit (16B units)

  __shared__ union {
    struct { unsigned char A[128 * 128]; unsigned char W[128 * 128]; } p1;  // 16K+16K
    struct { ushort Q[128][72]; ushort K[128][72]; } p2;                     // 36K
  } sm;

  const unsigned char* Ag = lhs8 + ((size_t)b * S_LEN + mrow0) * H_DIM;
  const unsigned char* Wg = wt8 + (size_t)th * 128 * H_DIM;

  f32x16 c2[4];
#pragma unroll
  for (int ni = 0; ni < 4; ++ni) c2[ni] = (f32x16){};

  for (int k0 = 0; k0 < H_DIM; k0 += 128) {
#pragma unroll
    for (int j = 0; j < 4; ++j) {
      const int r0 = w * 32 + j * 8;  // wave-uniform; 8 rows x 128B = 1KB per gload
      GLOAD16(Ag + (size_t)(r0 + lr8) * H_DIM + k0 + lsu * 16, &sm.p1.A[r0 * 128]);
      GLOAD16(Wg + (size_t)(r0 + lr8) * H_DIM + k0 + lsu * 16, &sm.p1.W[r0 * 128]);
    }
    __syncthreads();  // drains vmcnt -> tile ready
#pragma unroll
    for (int ks = 0; ks < 2; ++ks) {
      i32x8 a = frag8(sm.p1.A, w * 32 + l31, ks, hi2, l31);
#pragma unroll
      for (int ni = 0; ni < 4; ++ni) {
        i32x8 bb = frag8(sm.p1.W, ni * 32 + l31, ks, hi2, l31);
        c2[ni] = __builtin_amdgcn_mfma_scale_f32_32x32x64_f8f6f4(
            a, bb, c2[ni], 0, 0, 0, 0x7F, 0, 0x7F);
      }
    }
    __syncthreads();  // protect LDS overwrite next iter
  }

  // ---- bias + RoPE (table) into LDS bounce ----
  float bj2[4];
#pragma unroll
  for (int ni = 0; ni < 4; ++ni) bj2[ni] = bias[th * 128 + ni * 32 + l31];
  const float sgn = (l31 & 1) ? 1.0f : -1.0f;

#pragma unroll
  for (int reg = 0; reg < 16; ++reg) {
    int ml = w * 32 + (reg & 3) + 8 * (reg >> 2) + 4 * hi2;  // verified 32x32 row map
    int m_seq = mrow0 + ml;
#pragma unroll
    for (int ni = 0; ni < 2; ++ni) {
      float2 cs = rope[(size_t)m_seq * 64 + ni * 32 + l31];
      {  // q half: cols 0..63 (ni 0,1)
        float v = c2[ni][reg] + bj2[ni];
        float o = __shfl_xor(v, 1);
        sm.p2.Q[ml][ni * 32 + l31] = f2bf(v * cs.x + sgn * o * cs.y);
      }
      {  // k half: cols 64..127 (ni 2,3)
        float v = c2[ni + 2][reg] + bj2[ni + 2];
        float o = __shfl_xor(v, 1);
        sm.p2.K[ml][ni * 32 + l31] = f2bf(v * cs.x + sgn * o * cs.y);
      }
    }
  }
  __syncthreads();

  // ---- flush: bf16 bounce -> fp8, 8B coalesced cached stores (L2-resident for K2) ----
  unsigned char* qbase = Qb + ((size_t)(b * T_HEADS + th) * S_LEN + mrow0) * 64;
  unsigned char* kbase = Kb + ((size_t)(b * T_HEADS + th) * S_LEN + mrow0) * 64;
#pragma unroll
  for (int p = 0; p < 4; ++p) {
    int f = p * 256 + tid;
    int row = f >> 3, c8 = f & 7;
    uint2 q8 = fp8x8_from_bf16x8(*reinterpret_cast<const u32x4*>(&sm.p2.Q[row][c8 * 8]));
    uint2 k8 = fp8x8_from_bf16x8(*reinterpret_cast<const u32x4*>(&sm.p2.K[row][c8 * 8]));
    *reinterpret_cast<uint2*>(qbase + (size_t)row * 64 + c8 * 8) = q8;
    *reinterpret_cast<uint2*>(kbase + (size_t)row * 64 + c8 * 8) = k8;
  }
}

// ---- K2: logits = Q @ K^T (fp8, one 32x32x64 MFMA per tile pair); NT stores ----
__global__ __launch_bounds__(256, 4) void qk_logits(
    const unsigned char* __restrict__ Qb, const unsigned char* __restrict__ Kb,
    const float* __restrict__ amask, float* __restrict__ out) {
  const int x = blockIdx.x;        // 0..831
  const int xcd = x & 7;
  const int seq = x >> 3;          // 0..103
  const int grp = seq / 52;
  const int loc = seq % 52;        // 4 batches * 13 heads
  const int b = (xcd + 8 * grp) * 4 + loc / 13;
  const int th = loc % 13;
  const int bid = b * T_HEADS + th;
  const int tid = threadIdx.x;
  const int w = tid >> 6;
  const int lane = tid & 63;
  const int l31 = lane & 31;
  const int hi2 = lane >> 5;

  const unsigned char* qbase = Qb + (size_t)bid * S_LEN * 64;
  const unsigned char* kbase = Kb + (size_t)bid * S_LEN * 64;

  // A-frag (32x32x64 fp8): row = l31, 32 bytes at hi2*32; B identical (consistent-k).
  i32x8 qf[2];
#pragma unroll
  for (int mtile = 0; mtile < 2; ++mtile) {
    const unsigned char* p = qbase + (size_t)(w * 64 + mtile * 32 + l31) * 64 + hi2 * 32;
    union { u32x4 h[2]; i32x8 v; } u;
    u.h[0] = *reinterpret_cast<const u32x4*>(p);
    u.h[1] = *reinterpret_cast<const u32x4*>(p + 16);
    qf[mtile] = u.v;
  }

  const size_t outbase = (size_t)bid * (S_LEN * (size_t)S_LEN);
#pragma unroll 1
  for (int nt = 0; nt < 8; ++nt) {
    i32x8 kf;
    {
      const unsigned char* p = kbase + (size_t)(nt * 32 + l31) * 64 + hi2 * 32;
      union { u32x4 h[2]; i32x8 v; } u;
      u.h[0] = *reinterpret_cast<const u32x4*>(p);
      u.h[1] = *reinterpret_cast<const u32x4*>(p + 16);
      kf = u.v;
    }

    const int ncol = nt * 32 + l31;
    const float pad = amask[b * S_LEN + ncol];
    const float sub = (1.0f - pad) * NEGV;

#pragma unroll
    for (int mtile = 0; mtile < 2; ++mtile) {
      f32x16 c2 = {};
      c2 = __builtin_amdgcn_mfma_scale_f32_32x32x64_f8f6f4(
          qf[mtile], kf, c2, 0, 0, 0, 0x7F, 0, 0x7F);

#pragma unroll
      for (int reg = 0; reg < 16; ++reg) {
        int m = w * 64 + mtile * 32 + (reg & 3) + 8 * (reg >> 2) + 4 * hi2;
        float v = c2[reg] * pad - sub;
        if (m > ncol) v -= NEGV;  // tril(.., -1)
        __builtin_nontemporal_store(v * 0.125f, &out[outbase + (size_t)m * S_LEN + ncol]);
      }
    }
  }
}

// ---- fallback fused kernel (known-correct, no workspace) ----
__global__ __launch_bounds__(256, 1) void gp_fallback(
    const float* __restrict__ lhs, const float* __restrict__ Wd,
    const float* __restrict__ bias, const float* __restrict__ amask,
    float* __restrict__ out) {
  const int bid0 = blockIdx.x;
  const int bid = (bid0 & 7) * 104 + (bid0 >> 3);
  const int b = bid / T_HEADS;
  const int th = bid % T_HEADS;
  const int wcol0 = th * 128;
  const int tid = threadIdx.x;
  const int w = tid >> 6;
  const int lane = tid & 63;
  const int lo = lane & 15;
  const int hi = lane >> 4;
  const int l31 = lane & 31;
  const int hi2 = lane >> 5;

  __shared__ union {
    struct { ushort A[256][72]; ushort W[128][72]; } p1;
    struct { ushort Q[256][72]; ushort K[256][72]; } p2;
  } sm;
  __shared__ float mask_s[256];

  mask_s[tid] = amask[b * S_LEN + tid];

  f32x4 acc[4][8];
#pragma unroll
  for (int mi = 0; mi < 4; ++mi)
#pragma unroll
    for (int ni = 0; ni < 8; ++ni) acc[mi][ni] = (f32x4){0.f, 0.f, 0.f, 0.f};

  const float* Ab = lhs + (size_t)b * (S_LEN * H_DIM);
  const int wc4 = tid & 31, wrg = tid >> 5;
  for (int k0 = 0; k0 < H_DIM; k0 += 64) {
#pragma unroll
    for (int p = 0; p < 16; ++p) {
      int f = p * 256 + tid;
      int m = f >> 4, c4 = f & 15;
      float4 v = *reinterpret_cast<const float4*>(Ab + (size_t)m * H_DIM + k0 + c4 * 4);
      *reinterpret_cast<ushort4*>(&sm.p1.A[m][c4 * 4]) =
          make_ushort4(f2bf(v.x), f2bf(v.y), f2bf(v.z), f2bf(v.w));
    }
    {
      ushort wt[8][4];
#pragma unroll
      for (int r8 = 0; r8 < 8; ++r8) {
        float4 v = *reinterpret_cast<const float4*>(
            Wd + (size_t)(k0 + wrg * 8 + r8) * WN + wcol0 + wc4 * 4);
        wt[r8][0] = f2bf(v.x); wt[r8][1] = f2bf(v.y);
        wt[r8][2] = f2bf(v.z); wt[r8][3] = f2bf(v.w);
      }
#pragma unroll
      for (int cc = 0; cc < 4; ++cc) {
        *reinterpret_cast<ushort4*>(&sm.p1.W[wc4 * 4 + cc][wrg * 8]) =
            make_ushort4(wt[0][cc], wt[1][cc], wt[2][cc], wt[3][cc]);
        *reinterpret_cast<ushort4*>(&sm.p1.W[wc4 * 4 + cc][wrg * 8 + 4]) =
            make_ushort4(wt[4][cc], wt[5][cc], wt[6][cc], wt[7][cc]);
      }
    }
    __syncthreads();
#pragma unroll
    for (int kk = 0; kk < 2; ++kk) {
      bf16x8 af[4];
#pragma unroll
      for (int mi = 0; mi < 4; ++mi)
        af[mi] = *reinterpret_cast<const bf16x8*>(&sm.p1.A[w * 64 + mi * 16 + lo][kk * 32 + hi * 8]);
#pragma unroll
      for (int ni = 0; ni < 8; ++ni) {
        bf16x8 bfr = *reinterpret_cast<const bf16x8*>(&sm.p1.W[ni * 16 + lo][kk * 32 + hi * 8]);
#pragma unroll
        for (int mi = 0; mi < 4; ++mi)
          acc[mi][ni] = __builtin_amdgcn_mfma_f32_16x16x32_bf16(af[mi], bfr, acc[mi][ni], 0, 0, 0);
      }
    }
    __syncthreads();
  }

  float bj[8];
#pragma unroll
  for (int ni = 0; ni < 8; ++ni) bj[ni] = bias[wcol0 + ni * 16 + lo];

  float inv_[4];
#pragma unroll
  for (int ii = 0; ii < 4; ++ii)
    inv_[ii] = exp2f(-(float)(ii * 8 + (lo >> 1)) * 0.4152410118609203f);
  const float sgn = (lo & 1) ? 1.0f : -1.0f;

#pragma unroll
  for (int mi = 0; mi < 4; ++mi) {
#pragma unroll
    for (int r = 0; r < 4; ++r) {
      int m = w * 64 + mi * 16 + hi * 4 + r;
#pragma unroll
      for (int ii = 0; ii < 4; ++ii) {
        float sv, cv;
        __sincosf((float)m * inv_[ii], &sv, &cv);
        {
          float v = acc[mi][ii][r] + bj[ii];
          float o = __shfl_xor(v, 1);
          sm.p2.Q[m][ii * 16 + lo] = f2bf(v * cv + sgn * o * sv);
        }
        {
          float v = acc[mi][ii + 4][r] + bj[ii + 4];
          float o = __shfl_xor(v, 1);
          sm.p2.K[m][ii * 16 + lo] = f2bf(v * cv + sgn * o * sv);
        }
      }
    }
  }
  __syncthreads();

  bf16x8 qf2[2][4];
#pragma unroll
  for (int mtile = 0; mtile < 2; ++mtile)
#pragma unroll
    for (int ks = 0; ks < 4; ++ks)
      qf2[mtile][ks] = *reinterpret_cast<const bf16x8*>(
          &sm.p2.Q[w * 64 + mtile * 32 + l31][ks * 16 + hi2 * 8]);

  const size_t outbase = (size_t)bid * (S_LEN * (size_t)S_LEN);
#pragma unroll 1
  for (int nt = 0; nt < 8; ++nt) {
    bf16x8 kf2[4];
#pragma unroll
    for (int ks = 0; ks < 4; ++ks)
      kf2[ks] = *reinterpret_cast<const bf16x8*>(
          &sm.p2.K[nt * 32 + l31][ks * 16 + hi2 * 8]);

    const int ncol = nt * 32 + l31;
    const float pad = mask_s[ncol];
    const float sub = (1.0f - pad) * NEGV;

#pragma unroll
    for (int mtile = 0; mtile < 2; ++mtile) {
      f32x16 c2 = {};
#pragma unroll
      for (int ks = 0; ks < 4; ++ks)
        c2 = __builtin_amdgcn_mfma_f32_32x32x16_bf16(qf2[mtile][ks], kf2[ks], c2, 0, 0, 0);

#pragma unroll
      for (int reg = 0; reg < 16; ++reg) {
        int m = w * 64 + mtile * 32 + (reg & 3) + 8 * (reg >> 2) + 4 * hi2;
        float v = c2[reg] * pad - sub;
        if (m > ncol) v -= NEGV;
        __builtin_nontemporal_store(v * 0.125f, &out[outbase + (size_t)m * S_LEN + ncol]);
      }
    }
  }
}

extern "C" void kernel_launch(void* const* d_in, const int* in_sizes, int n_in,
                              void* d_out, int out_size, void* d_ws, size_t ws_size,
                              hipStream_t stream) {
  const float* lhs = (const float*)d_in[0];    // (64,256,768) f32
  const float* Wd = (const float*)d_in[1];     // (768,1664) f32
  const float* bias = (const float*)d_in[2];   // (1664,) f32
  const float* amask = (const float*)d_in[3];  // (64,256) f32
  float* out = (float*)d_out;                  // (64,13,256,256) f32

  const size_t rope_bytes = (size_t)256 * 64 * sizeof(float2);   // 128 KB
  const size_t qk_bytes = (size_t)64 * T_HEADS * S_LEN * 64;     // 13.63 MB each (fp8)
  const size_t lhs8_bytes = (size_t)64 * S_LEN * H_DIM;          // 12.58 MB
  const size_t wt8_bytes = (size_t)WN * H_DIM;                   // 1.28 MB
  const size_t need = rope_bytes + 2 * qk_bytes + lhs8_bytes + wt8_bytes;

  if (ws_size >= need) {
    float2* rope = (float2*)d_ws;
    unsigned char* qb = (unsigned char*)d_ws + rope_bytes;
    unsigned char* kb = qb + qk_bytes;
    unsigned char* lhs8 = kb + qk_bytes;
    unsigned char* wt8 = lhs8 + lhs8_bytes;
    prep_all<<<dim3(PREP_LHS_BLOCKS + PREP_WT_BLOCKS + PREP_ROPE_BLOCKS), 256, 0, stream>>>(
        lhs, Wd, lhs8, wt8, rope);
    gemm_rope<<<dim3(128 * T_HEADS), 256, 0, stream>>>(lhs8, wt8, bias, rope, qb, kb);
    qk_logits<<<dim3(64 * T_HEADS), 256, 0, stream>>>(qb, kb, amask, out);
  } else {
    gp_fallback<<<dim3(64 * T_HEADS), 256, 0, stream>>>(lhs, Wd, bias, amask, out);
  }
}

// Round 13
// 82.906 us; speedup vs baseline: 1.6545x; 1.1930x over previous
//
#include <hip/hip_runtime.h>

#define S_LEN 256
#define H_DIM 768
#define T_HEADS 13
#define WN 1664
#define NEGV 1.0e12f

typedef __bf16 bf16x8 __attribute__((ext_vector_type(8)));
typedef float f32x4 __attribute__((ext_vector_type(4)));
typedef float f32x16 __attribute__((ext_vector_type(16)));
typedef unsigned int u32x4 __attribute__((ext_vector_type(4)));
typedef int i32x8 __attribute__((ext_vector_type(8)));

static __device__ __forceinline__ ushort f2bf(float x) {
  unsigned u = __float_as_uint(x);
  return (ushort)((u + 0x7FFFu + ((u >> 16) & 1u)) >> 16);
}

// async global->LDS, 16B per lane; LDS dest = wave-uniform base + lane*16
#define GLOAD16(gp, lp)                                                        \
  __builtin_amdgcn_global_load_lds(                                            \
      (const __attribute__((address_space(1))) unsigned int*)(gp),             \
      (__attribute__((address_space(3))) unsigned int*)(lp), 16, 0, 0)

#define PREP_LHS_BLOCKS 6144   // (64*256*768)/8/256
#define PREP_WT_BLOCKS 312     // 12 * 26
#define PREP_ROPE_BLOCKS 16

// ---- prep (fused): lhs f32->fp8 copy + W transpose f32->fp8 + RoPE table ----
__global__ __launch_bounds__(256) void prep_all(const float* __restrict__ lhs,
                                                const float* __restrict__ W,
                                                unsigned char* __restrict__ lhs8,
                                                unsigned char* __restrict__ wt8,
                                                float2* __restrict__ rope) {
  const int tid = threadIdx.x;
  const unsigned bx = blockIdx.x;
  if (bx < PREP_LHS_BLOCKS) {
    size_t base = ((size_t)bx * 256 + tid) * 8;
    float4 v0 = *reinterpret_cast<const float4*>(lhs + base);
    float4 v1 = *reinterpret_cast<const float4*>(lhs + base + 4);
    int d0 = __builtin_amdgcn_cvt_pk_fp8_f32(v0.x, v0.y, 0, false);
    d0 = __builtin_amdgcn_cvt_pk_fp8_f32(v0.z, v0.w, d0, true);
    int d1 = __builtin_amdgcn_cvt_pk_fp8_f32(v1.x, v1.y, 0, false);
    d1 = __builtin_amdgcn_cvt_pk_fp8_f32(v1.z, v1.w, d1, true);
    uint2 u = make_uint2((unsigned)d0, (unsigned)d1);
    *reinterpret_cast<uint2*>(lhs8 + base) = u;
    return;
  }
  if (bx < PREP_LHS_BLOCKS + PREP_WT_BLOCKS) {
    __shared__ float T[64][68];
    const int blk = bx - PREP_LHS_BLOCKS;
    const int k0 = (blk % 12) * 64, c0 = (blk / 12) * 64;
#pragma unroll
    for (int p = 0; p < 4; ++p) {
      int f = p * 256 + tid;
      int r = f >> 4, cg = f & 15;
      float4 v = *reinterpret_cast<const float4*>(W + (size_t)(k0 + r) * WN + c0 + cg * 4);
      T[r][cg * 4 + 0] = v.x; T[r][cg * 4 + 1] = v.y;
      T[r][cg * 4 + 2] = v.z; T[r][cg * 4 + 3] = v.w;
    }
    __syncthreads();
    const int orow = tid >> 2, kq = tid & 3;
    float tf[16];
#pragma unroll
    for (int j = 0; j < 16; ++j) tf[j] = T[kq * 16 + j][orow];
    int d[4];
#pragma unroll
    for (int q = 0; q < 4; ++q) {
      d[q] = __builtin_amdgcn_cvt_pk_fp8_f32(tf[q * 4], tf[q * 4 + 1], 0, false);
      d[q] = __builtin_amdgcn_cvt_pk_fp8_f32(tf[q * 4 + 2], tf[q * 4 + 3], d[q], true);
    }
    uint4 u = make_uint4((unsigned)d[0], (unsigned)d[1], (unsigned)d[2], (unsigned)d[3]);
    *reinterpret_cast<uint4*>(wt8 + (size_t)(c0 + orow) * H_DIM + k0 + kq * 16) = u;
    return;
  }
  // RoPE table: rope[m][c] = (cos(m*inv[c>>1]), sin(m*inv[c>>1])), m<256, c<64
  const int blk = bx - (PREP_LHS_BLOCKS + PREP_WT_BLOCKS);
  const int row = blk * 16 + (tid >> 4);
  const int cq = (tid & 15) * 4;
#pragma unroll
  for (int q = 0; q < 4; ++q) {
    int c = cq + q;
    float inv = exp2f(-(float)(c >> 1) * 0.4152410118609203f);  // log2(1e4)/32
    float sv, cv;
    __sincosf((float)row * inv, &sv, &cv);
    rope[(size_t)row * 64 + c] = make_float2(cv, sv);
  }
}

// fp8 MFMA operand: row-slice read with unit-XOR swizzle (both-sides involution)
static __device__ __forceinline__ i32x8 frag8(const unsigned char* base, int row,
                                              int ks, int hi2, int l31) {
  union { u32x4 h[2]; i32x8 v; } u;
  const int u0 = (ks * 4 + hi2 * 2 + 0) ^ (l31 & 7);
  const int u1 = (ks * 4 + hi2 * 2 + 1) ^ (l31 & 7);
  u.h[0] = *reinterpret_cast<const u32x4*>(base + row * 128 + u0 * 16);
  u.h[1] = *reinterpret_cast<const u32x4*>(base + row * 128 + u1 * 16);
  return u.v;
}

// ---- fused main: fp8 MX GEMM (M=256,N=128,BK=128) + bias + RoPE(table)
//      -> bf16 Q/K in LDS -> QK^T (bf16) -> mask/tril -> NT stores ----
__global__ __launch_bounds__(256, 2) void gp_fused(
    const unsigned char* __restrict__ lhs8, const unsigned char* __restrict__ wt8,
    const float* __restrict__ bias, const float2* __restrict__ rope,
    const float* __restrict__ amask, float* __restrict__ out) {
  const int x = blockIdx.x;        // 0..831
  const int xcd = x & 7;
  const int seq = x >> 3;          // 0..103
  const int grp = seq / 52;
  const int loc = seq % 52;        // 4 batches * 13 heads
  const int b = (xcd + 8 * grp) * 4 + loc / 13;
  const int th = loc % 13;
  const int bid = b * T_HEADS + th;
  const int tid = threadIdx.x;
  const int w = tid >> 6;
  const int lane = tid & 63;
  const int l31 = lane & 31;
  const int hi2 = lane >> 5;
  const int lr8 = lane >> 3;              // 0..7 (row within 8-row stripe)
  const int lsu = (lane & 7) ^ lr8;       // pre-swizzled source unit (16B units)

  __shared__ union {
    struct { unsigned char A[256 * 128]; unsigned char W[128 * 128]; } p1;  // 32K+16K
    struct { ushort Q[256][72]; ushort K[256][72]; } p2;                     // 72K
  } sm;

  const unsigned char* Ag = lhs8 + (size_t)b * S_LEN * H_DIM;
  const unsigned char* Wg = wt8 + (size_t)th * 128 * H_DIM;

  f32x16 c2[2][4];
#pragma unroll
  for (int mt = 0; mt < 2; ++mt)
#pragma unroll
    for (int ni = 0; ni < 4; ++ni) c2[mt][ni] = (f32x16){};

  // ---- phase A: GEMM, 6 x BK=128 steps ----
  for (int k0 = 0; k0 < H_DIM; k0 += 128) {
#pragma unroll
    for (int j = 0; j < 8; ++j) {  // A: wave w stages rows w*64 .. w*64+63
      const int r0 = w * 64 + j * 8;
      GLOAD16(Ag + (size_t)(r0 + lr8) * H_DIM + k0 + lsu * 16, &sm.p1.A[r0 * 128]);
    }
#pragma unroll
    for (int j = 0; j < 4; ++j) {  // W: wave w stages rows w*32 .. w*32+31
      const int r0 = w * 32 + j * 8;
      GLOAD16(Wg + (size_t)(r0 + lr8) * H_DIM + k0 + lsu * 16, &sm.p1.W[r0 * 128]);
    }
    __syncthreads();  // drains vmcnt -> tile ready
#pragma unroll
    for (int ks = 0; ks < 2; ++ks) {
#pragma unroll
      for (int mt = 0; mt < 2; ++mt) {
        i32x8 a = frag8(sm.p1.A, w * 64 + mt * 32 + l31, ks, hi2, l31);
#pragma unroll
        for (int ni = 0; ni < 4; ++ni) {
          i32x8 bb = frag8(sm.p1.W, ni * 32 + l31, ks, hi2, l31);
          c2[mt][ni] = __builtin_amdgcn_mfma_scale_f32_32x32x64_f8f6f4(
              a, bb, c2[mt][ni], 0, 0, 0, 0x7F, 0, 0x7F);
        }
      }
    }
    __syncthreads();  // protect LDS overwrite (next iter / epilogue)
  }

  // ---- phase B: bias + RoPE (table) -> bf16 Q/K in LDS ----
  float bj2[4];
#pragma unroll
  for (int ni = 0; ni < 4; ++ni) bj2[ni] = bias[th * 128 + ni * 32 + l31];
  const float sgn = (l31 & 1) ? 1.0f : -1.0f;

#pragma unroll
  for (int mt = 0; mt < 2; ++mt) {
#pragma unroll
    for (int reg = 0; reg < 16; ++reg) {
      int ml = w * 64 + mt * 32 + (reg & 3) + 8 * (reg >> 2) + 4 * hi2;  // 0..255
#pragma unroll
      for (int ni = 0; ni < 2; ++ni) {
        float2 cs = rope[(size_t)ml * 64 + ni * 32 + l31];
        {  // q half: cols 0..63 (ni 0,1)
          float v = c2[mt][ni][reg] + bj2[ni];
          float o = __shfl_xor(v, 1);
          sm.p2.Q[ml][ni * 32 + l31] = f2bf(v * cs.x + sgn * o * cs.y);
        }
        {  // k half: cols 64..127 (ni 2,3)
          float v = c2[mt][ni + 2][reg] + bj2[ni + 2];
          float o = __shfl_xor(v, 1);
          sm.p2.K[ml][ni * 32 + l31] = f2bf(v * cs.x + sgn * o * cs.y);
        }
      }
    }
  }
  __syncthreads();

  // ---- phase C: logits = Q @ K^T (bf16 32x32x16), mask, scale, NT store ----
  bf16x8 qf2[2][4];
#pragma unroll
  for (int mtile = 0; mtile < 2; ++mtile)
#pragma unroll
    for (int ks = 0; ks < 4; ++ks)
      qf2[mtile][ks] = *reinterpret_cast<const bf16x8*>(
          &sm.p2.Q[w * 64 + mtile * 32 + l31][ks * 16 + hi2 * 8]);

  const size_t outbase = (size_t)bid * (S_LEN * (size_t)S_LEN);
#pragma unroll 1
  for (int nt = 0; nt < 8; ++nt) {
    bf16x8 kf2[4];
#pragma unroll
    for (int ks = 0; ks < 4; ++ks)
      kf2[ks] = *reinterpret_cast<const bf16x8*>(
          &sm.p2.K[nt * 32 + l31][ks * 16 + hi2 * 8]);

    const int ncol = nt * 32 + l31;
    const float pad = amask[b * S_LEN + ncol];
    const float sub = (1.0f - pad) * NEGV;

#pragma unroll
    for (int mtile = 0; mtile < 2; ++mtile) {
      f32x16 cq = {};
#pragma unroll
      for (int ks = 0; ks < 4; ++ks)
        cq = __builtin_amdgcn_mfma_f32_32x32x16_bf16(qf2[mtile][ks], kf2[ks], cq, 0, 0, 0);

#pragma unroll
      for (int reg = 0; reg < 16; ++reg) {
        int m = w * 64 + mtile * 32 + (reg & 3) + 8 * (reg >> 2) + 4 * hi2;
        float v = cq[reg] * pad - sub;
        if (m > ncol) v -= NEGV;  // tril(.., -1)
        __builtin_nontemporal_store(v * 0.125f, &out[outbase + (size_t)m * S_LEN + ncol]);
      }
    }
  }
}

// ---- fallback fused kernel (known-correct, no workspace) ----
__global__ __launch_bounds__(256, 1) void gp_fallback(
    const float* __restrict__ lhs, const float* __restrict__ Wd,
    const float* __restrict__ bias, const float* __restrict__ amask,
    float* __restrict__ out) {
  const int bid0 = blockIdx.x;
  const int bid = (bid0 & 7) * 104 + (bid0 >> 3);
  const int b = bid / T_HEADS;
  const int th = bid % T_HEADS;
  const int wcol0 = th * 128;
  const int tid = threadIdx.x;
  const int w = tid >> 6;
  const int lane = tid & 63;
  const int lo = lane & 15;
  const int hi = lane >> 4;
  const int l31 = lane & 31;
  const int hi2 = lane >> 5;

  __shared__ union {
    struct { ushort A[256][72]; ushort W[128][72]; } p1;
    struct { ushort Q[256][72]; ushort K[256][72]; } p2;
  } sm;
  __shared__ float mask_s[256];

  mask_s[tid] = amask[b * S_LEN + tid];

  f32x4 acc[4][8];
#pragma unroll
  for (int mi = 0; mi < 4; ++mi)
#pragma unroll
    for (int ni = 0; ni < 8; ++ni) acc[mi][ni] = (f32x4){0.f, 0.f, 0.f, 0.f};

  const float* Ab = lhs + (size_t)b * (S_LEN * H_DIM);
  const int wc4 = tid & 31, wrg = tid >> 5;
  for (int k0 = 0; k0 < H_DIM; k0 += 64) {
#pragma unroll
    for (int p = 0; p < 16; ++p) {
      int f = p * 256 + tid;
      int m = f >> 4, c4 = f & 15;
      float4 v = *reinterpret_cast<const float4*>(Ab + (size_t)m * H_DIM + k0 + c4 * 4);
      *reinterpret_cast<ushort4*>(&sm.p1.A[m][c4 * 4]) =
          make_ushort4(f2bf(v.x), f2bf(v.y), f2bf(v.z), f2bf(v.w));
    }
    {
      ushort wt[8][4];
#pragma unroll
      for (int r8 = 0; r8 < 8; ++r8) {
        float4 v = *reinterpret_cast<const float4*>(
            Wd + (size_t)(k0 + wrg * 8 + r8) * WN + wcol0 + wc4 * 4);
        wt[r8][0] = f2bf(v.x); wt[r8][1] = f2bf(v.y);
        wt[r8][2] = f2bf(v.z); wt[r8][3] = f2bf(v.w);
      }
#pragma unroll
      for (int cc = 0; cc < 4; ++cc) {
        *reinterpret_cast<ushort4*>(&sm.p1.W[wc4 * 4 + cc][wrg * 8]) =
            make_ushort4(wt[0][cc], wt[1][cc], wt[2][cc], wt[3][cc]);
        *reinterpret_cast<ushort4*>(&sm.p1.W[wc4 * 4 + cc][wrg * 8 + 4]) =
            make_ushort4(wt[4][cc], wt[5][cc], wt[6][cc], wt[7][cc]);
      }
    }
    __syncthreads();
#pragma unroll
    for (int kk = 0; kk < 2; ++kk) {
      bf16x8 af[4];
#pragma unroll
      for (int mi = 0; mi < 4; ++mi)
        af[mi] = *reinterpret_cast<const bf16x8*>(&sm.p1.A[w * 64 + mi * 16 + lo][kk * 32 + hi * 8]);
#pragma unroll
      for (int ni = 0; ni < 8; ++ni) {
        bf16x8 bfr = *reinterpret_cast<const bf16x8*>(&sm.p1.W[ni * 16 + lo][kk * 32 + hi * 8]);
#pragma unroll
        for (int mi = 0; mi < 4; ++mi)
          acc[mi][ni] = __builtin_amdgcn_mfma_f32_16x16x32_bf16(af[mi], bfr, acc[mi][ni], 0, 0, 0);
      }
    }
    __syncthreads();
  }

  float bj[8];
#pragma unroll
  for (int ni = 0; ni < 8; ++ni) bj[ni] = bias[wcol0 + ni * 16 + lo];

  float inv_[4];
#pragma unroll
  for (int ii = 0; ii < 4; ++ii)
    inv_[ii] = exp2f(-(float)(ii * 8 + (lo >> 1)) * 0.4152410118609203f);
  const float sgn = (lo & 1) ? 1.0f : -1.0f;

#pragma unroll
  for (int mi = 0; mi < 4; ++mi) {
#pragma unroll
    for (int r = 0; r < 4; ++r) {
      int m = w * 64 + mi * 16 + hi * 4 + r;
#pragma unroll
      for (int ii = 0; ii < 4; ++ii) {
        float sv, cv;
        __sincosf((float)m * inv_[ii], &sv, &cv);
        {
          float v = acc[mi][ii][r] + bj[ii];
          float o = __shfl_xor(v, 1);
          sm.p2.Q[m][ii * 16 + lo] = f2bf(v * cv + sgn * o * sv);
        }
        {
          float v = acc[mi][ii + 4][r] + bj[ii + 4];
          float o = __shfl_xor(v, 1);
          sm.p2.K[m][ii * 16 + lo] = f2bf(v * cv + sgn * o * sv);
        }
      }
    }
  }
  __syncthreads();

  bf16x8 qf2[2][4];
#pragma unroll
  for (int mtile = 0; mtile < 2; ++mtile)
#pragma unroll
    for (int ks = 0; ks < 4; ++ks)
      qf2[mtile][ks] = *reinterpret_cast<const bf16x8*>(
          &sm.p2.Q[w * 64 + mtile * 32 + l31][ks * 16 + hi2 * 8]);

  const size_t outbase = (size_t)bid * (S_LEN * (size_t)S_LEN);
#pragma unroll 1
  for (int nt = 0; nt < 8; ++nt) {
    bf16x8 kf2[4];
#pragma unroll
    for (int ks = 0; ks < 4; ++ks)
      kf2[ks] = *reinterpret_cast<const bf16x8*>(
          &sm.p2.K[nt * 32 + l31][ks * 16 + hi2 * 8]);

    const int ncol = nt * 32 + l31;
    const float pad = mask_s[ncol];
    const float sub = (1.0f - pad) * NEGV;

#pragma unroll
    for (int mtile = 0; mtile < 2; ++mtile) {
      f32x16 cq = {};
#pragma unroll
      for (int ks = 0; ks < 4; ++ks)
        cq = __builtin_amdgcn_mfma_f32_32x32x16_bf16(qf2[mtile][ks], kf2[ks], cq, 0, 0, 0);

#pragma unroll
      for (int reg = 0; reg < 16; ++reg) {
        int m = w * 64 + mtile * 32 + (reg & 3) + 8 * (reg >> 2) + 4 * hi2;
        float v = cq[reg] * pad - sub;
        if (m > ncol) v -= NEGV;
        __builtin_nontemporal_store(v * 0.125f, &out[outbase + (size_t)m * S_LEN + ncol]);
      }
    }
  }
}

extern "C" void kernel_launch(void* const* d_in, const int* in_sizes, int n_in,
                              void* d_out, int out_size, void* d_ws, size_t ws_size,
                              hipStream_t stream) {
  const float* lhs = (const float*)d_in[0];    // (64,256,768) f32
  const float* Wd = (const float*)d_in[1];     // (768,1664) f32
  const float* bias = (const float*)d_in[2];   // (1664,) f32
  const float* amask = (const float*)d_in[3];  // (64,256) f32
  float* out = (float*)d_out;                  // (64,13,256,256) f32

  const size_t rope_bytes = (size_t)256 * 64 * sizeof(float2);   // 128 KB
  const size_t lhs8_bytes = (size_t)64 * S_LEN * H_DIM;          // 12.58 MB
  const size_t wt8_bytes = (size_t)WN * H_DIM;                   // 1.28 MB
  const size_t need = rope_bytes + lhs8_bytes + wt8_bytes;       // ~14 MB

  if (ws_size >= need) {
    float2* rope = (float2*)d_ws;
    unsigned char* lhs8 = (unsigned char*)d_ws + rope_bytes;
    unsigned char* wt8 = lhs8 + lhs8_bytes;
    prep_all<<<dim3(PREP_LHS_BLOCKS + PREP_WT_BLOCKS + PREP_ROPE_BLOCKS), 256, 0, stream>>>(
        lhs, Wd, lhs8, wt8, rope);
    gp_fused<<<dim3(64 * T_HEADS), 256, 0, stream>>>(lhs8, wt8, bias, rope, amask, out);
  } else {
    gp_fallback<<<dim3(64 * T_HEADS), 256, 0, stream>>>(lhs, Wd, bias, amask, out);
  }
}